// Round 5
// baseline (332.752 us; speedup 1.0000x reference)
//
#include <hip/hip_runtime.h>
#include <math.h>

// Problem constants
#define BB 32
#define NN 1024
#define DD 768
#define KK 512
#define MM (BB * NN)  // 32768 token rows

typedef _Float16 half8 __attribute__((ext_vector_type(8)));
typedef _Float16 half4 __attribute__((ext_vector_type(4)));
typedef float floatx4 __attribute__((ext_vector_type(4)));

// async global(16B) -> LDS, per-lane dest = uniform base + lane*16
__device__ __forceinline__ void load_lds16(const void* g, void* l) {
    __builtin_amdgcn_global_load_lds(
        (const __attribute__((address_space(1))) unsigned int*)g,
        (__attribute__((address_space(3))) unsigned int*)l, 16, 0, 0);
}

// ---------------------------------------------------------------------------
// cast fp32 -> fp16 (codebook only)
// ---------------------------------------------------------------------------
__global__ __launch_bounds__(256) void cast_f32_f16(const float* __restrict__ src,
                                                    _Float16* __restrict__ dst,
                                                    int n8) {
    int i = blockIdx.x * 256 + threadIdx.x;
    if (i >= n8) return;
    float4 a = ((const float4*)src)[2 * i];
    float4 b = ((const float4*)src)[2 * i + 1];
    half8 h;
    h[0] = (_Float16)a.x; h[1] = (_Float16)a.y; h[2] = (_Float16)a.z; h[3] = (_Float16)a.w;
    h[4] = (_Float16)b.x; h[5] = (_Float16)b.y; h[6] = (_Float16)b.z; h[7] = (_Float16)b.w;
    ((half8*)dst)[i] = h;
}

// ---------------------------------------------------------------------------
// csq[k] = sum_d codebook[k][d]^2
// ---------------------------------------------------------------------------
__global__ __launch_bounds__(256) void csq_kernel(const float* __restrict__ cb,
                                                  float* __restrict__ csq) {
    int k = blockIdx.x;
    const float* row = cb + (size_t)k * DD;
    float s = 0.f;
    for (int d = threadIdx.x; d < DD; d += 256) {
        float v = row[d];
        s += v * v;
    }
    #pragma unroll
    for (int off = 32; off > 0; off >>= 1) s += __shfl_down(s, off);
    __shared__ float sm[4];
    int lane = threadIdx.x & 63, wid = threadIdx.x >> 6;
    if (lane == 0) sm[wid] = s;
    __syncthreads();
    if (threadIdx.x == 0) csq[k] = sm[0] + sm[1] + sm[2] + sm[3];
}

// ---------------------------------------------------------------------------
// FUSED v3: barrier-free K-loop.
// Block = 512 thr (8 waves) = 64 tokens x all 512 k; X staged ONCE in LDS
// (fp16, [24][64][40], 120 KB); codebook fragments loaded global->VGPR,
// triple-buffered, no __syncthreads in the d-loop. Also emits Xt[b][d][n]
// (byproduct transpose) and St[b][k][n] after in-register softmax.
// Wave w: m-half wm=(w&1)*32, k-slab wk=(w>>1)*128. acc 2x8 tiles.
// ---------------------------------------------------------------------------
__global__ __launch_bounds__(512, 2) void fused_logits_softmax(
    const float* __restrict__ X,        // [M, D] fp32
    const _Float16* __restrict__ Cbh,   // [K, D] fp16
    const float* __restrict__ csq,      // [K]
    _Float16* __restrict__ St,          // [B, K, N] fp16
    _Float16* __restrict__ Xt)          // [B, D, N] fp16
{
    __shared__ _Float16 Xs[24][64][40]; // 120 KB; 80B rows: 16B-aligned, 2-way banks
    __shared__ float redbuf[8][32];

    const int t = threadIdx.x;
    const int w = t >> 6;
    const int lane = t & 63;
    const int l15 = lane & 15;
    const int quad = lane >> 4;
    const int wm = (w & 1) * 32;        // token half
    const int wk = (w >> 1) * 128;      // k slab
    const int gm0 = blockIdx.x * 64;
    const int b = gm0 >> 10;
    const int nbase = gm0 & 1023;

    // ---- stage ALL X for this block (fp32 -> fp16), one barrier total ----
    {
        const int m = t >> 3;           // 0..63
        const int dl = (t & 7) * 4;     // 0..28
        const float* src = X + (size_t)(gm0 + m) * DD + dl;
        #pragma unroll 4
        for (int c = 0; c < 24; c++) {
            float4 v = *(const float4*)(src + c * 32);
            half4 h;
            h[0] = (_Float16)v.x; h[1] = (_Float16)v.y;
            h[2] = (_Float16)v.z; h[3] = (_Float16)v.w;
            *(half4*)&Xs[c][m][dl] = h;
        }
    }

    float cs[8];
    #pragma unroll
    for (int ki = 0; ki < 8; ki++) cs[ki] = csq[wk + ki * 16 + l15];

    __syncthreads();

    // ---- barrier-free d-loop: codebook direct global->VGPR, depth-3 pipeline ----
    const _Float16* cbl = Cbh + (size_t)(wk + l15) * DD + quad * 8;
    half8 b0[8], b1[8], b2[8];
    #pragma unroll
    for (int ki = 0; ki < 8; ki++) {
        const _Float16* p = cbl + (size_t)ki * 16 * DD;
        b0[ki] = *(const half8*)(p);
        b1[ki] = *(const half8*)(p + 32);
        b2[ki] = *(const half8*)(p + 64);
    }

    floatx4 acc[2][8] = {};

    for (int c = 0; c < 24; c += 3) {
        int c3 = (c + 3 < 24) ? c + 3 : 0;   // tail: harmless dup loads
        int c4 = (c + 4 < 24) ? c + 4 : 0;
        int c5 = (c + 5 < 24) ? c + 5 : 0;
        // chunk c (b0)
        {
            half8 a0 = *(half8*)&Xs[c][wm + l15][quad * 8];
            half8 a1 = *(half8*)&Xs[c][wm + 16 + l15][quad * 8];
            #pragma unroll
            for (int ki = 0; ki < 8; ki++) {
                acc[0][ki] = __builtin_amdgcn_mfma_f32_16x16x32_f16(a0, b0[ki], acc[0][ki], 0, 0, 0);
                acc[1][ki] = __builtin_amdgcn_mfma_f32_16x16x32_f16(a1, b0[ki], acc[1][ki], 0, 0, 0);
            }
            #pragma unroll
            for (int ki = 0; ki < 8; ki++)
                b0[ki] = *(const half8*)(cbl + (size_t)ki * 16 * DD + c3 * 32);
        }
        // chunk c+1 (b1)
        {
            half8 a0 = *(half8*)&Xs[c + 1][wm + l15][quad * 8];
            half8 a1 = *(half8*)&Xs[c + 1][wm + 16 + l15][quad * 8];
            #pragma unroll
            for (int ki = 0; ki < 8; ki++) {
                acc[0][ki] = __builtin_amdgcn_mfma_f32_16x16x32_f16(a0, b1[ki], acc[0][ki], 0, 0, 0);
                acc[1][ki] = __builtin_amdgcn_mfma_f32_16x16x32_f16(a1, b1[ki], acc[1][ki], 0, 0, 0);
            }
            #pragma unroll
            for (int ki = 0; ki < 8; ki++)
                b1[ki] = *(const half8*)(cbl + (size_t)ki * 16 * DD + c4 * 32);
        }
        // chunk c+2 (b2)
        {
            half8 a0 = *(half8*)&Xs[c + 2][wm + l15][quad * 8];
            half8 a1 = *(half8*)&Xs[c + 2][wm + 16 + l15][quad * 8];
            #pragma unroll
            for (int ki = 0; ki < 8; ki++) {
                acc[0][ki] = __builtin_amdgcn_mfma_f32_16x16x32_f16(a0, b2[ki], acc[0][ki], 0, 0, 0);
                acc[1][ki] = __builtin_amdgcn_mfma_f32_16x16x32_f16(a1, b2[ki], acc[1][ki], 0, 0, 0);
            }
            #pragma unroll
            for (int ki = 0; ki < 8; ki++)
                b2[ki] = *(const half8*)(cbl + (size_t)ki * 16 * DD + c5 * 32);
        }
    }

    // ---- byproduct: Xt[b][d][n] slice from LDS (overlaps softmax phase) ----
    for (int i = t; i < 6144; i += 512) {
        int d = i >> 3;
        int ng = (i & 7) * 8;
        half8 o;
        #pragma unroll
        for (int j = 0; j < 8; j++) o[j] = Xs[d >> 5][ng + j][d & 31];
        *(half8*)&Xt[((size_t)b * DD + d) * NN + nbase + ng] = o;
    }

    // ---- softmax over k=512 ----
    // logit = 2*acc - cs;  C/D: k = wk + ki*16 + l15, m-local = wm + mi*16 + quad*4 + r
    float pmax[2][4];
    #pragma unroll
    for (int mi = 0; mi < 2; mi++)
        #pragma unroll
        for (int r = 0; r < 4; r++) {
            float m = -1e30f;
            #pragma unroll
            for (int ki = 0; ki < 8; ki++)
                m = fmaxf(m, 2.f * acc[mi][ki][r] - cs[ki]);
            pmax[mi][r] = m;
        }
    #pragma unroll
    for (int off = 1; off < 16; off <<= 1)
        #pragma unroll
        for (int mi = 0; mi < 2; mi++)
            #pragma unroll
            for (int r = 0; r < 4; r++)
                pmax[mi][r] = fmaxf(pmax[mi][r], __shfl_xor(pmax[mi][r], off));
    if (l15 == 0) {
        #pragma unroll
        for (int mi = 0; mi < 2; mi++)
            #pragma unroll
            for (int r = 0; r < 4; r++)
                redbuf[w][mi * 16 + quad * 4 + r] = pmax[mi][r];
    }
    __syncthreads();
    float gmax[2][4];
    #pragma unroll
    for (int mi = 0; mi < 2; mi++)
        #pragma unroll
        for (int r = 0; r < 4; r++) {
            int idx = mi * 16 + quad * 4 + r;
            int wb = w & 1;
            gmax[mi][r] = fmaxf(fmaxf(redbuf[wb][idx], redbuf[wb + 2][idx]),
                                fmaxf(redbuf[wb + 4][idx], redbuf[wb + 6][idx]));
        }
    __syncthreads();  // redbuf reuse

    float psum[2][4] = {};
    #pragma unroll
    for (int mi = 0; mi < 2; mi++)
        #pragma unroll
        for (int ki = 0; ki < 8; ki++) {
            floatx4 e;
            #pragma unroll
            for (int r = 0; r < 4; r++) {
                e[r] = __expf(2.f * acc[mi][ki][r] - cs[ki] - gmax[mi][r]);
                psum[mi][r] += e[r];
            }
            acc[mi][ki] = e;
        }
    #pragma unroll
    for (int off = 1; off < 16; off <<= 1)
        #pragma unroll
        for (int mi = 0; mi < 2; mi++)
            #pragma unroll
            for (int r = 0; r < 4; r++)
                psum[mi][r] += __shfl_xor(psum[mi][r], off);
    if (l15 == 0) {
        #pragma unroll
        for (int mi = 0; mi < 2; mi++)
            #pragma unroll
            for (int r = 0; r < 4; r++)
                redbuf[w][mi * 16 + quad * 4 + r] = psum[mi][r];
    }
    __syncthreads();
    float ginv[2][4];
    #pragma unroll
    for (int mi = 0; mi < 2; mi++)
        #pragma unroll
        for (int r = 0; r < 4; r++) {
            int idx = mi * 16 + quad * 4 + r;
            int wb = w & 1;
            ginv[mi][r] = 1.f / (redbuf[wb][idx] + redbuf[wb + 2][idx] +
                                 redbuf[wb + 4][idx] + redbuf[wb + 6][idx]);
        }

    // ---- scale + transposed store: St[b][k][n] ----
    #pragma unroll
    for (int mi = 0; mi < 2; mi++)
        #pragma unroll
        for (int ki = 0; ki < 8; ki++) {
            half4 s4;
            #pragma unroll
            for (int r = 0; r < 4; r++)
                s4[r] = (_Float16)(acc[mi][ki][r] * ginv[mi][r]);
            int k = wk + ki * 16 + l15;
            *(half4*)&St[((size_t)b * KK + k) * NN + nbase + wm + mi * 16 + quad * 4] = s4;
        }
}

// ---------------------------------------------------------------------------
// GEMM2 v3: out[b][k][d] = sum_n St[b][k][n] * Xt[b][d][n]
// 128x128 tile, BK=64, DMA staging with XOR-swizzled source columns so
// fragment ds_read_b128 is 2-way (free) instead of 16-way conflicted.
// stored[r][j] = global[r][j ^ (r&7)]  (j = 8-half column group)
// ---------------------------------------------------------------------------
__global__ __launch_bounds__(256) void gemm2_mfma(const _Float16* __restrict__ St,
                                                  const _Float16* __restrict__ Xt,
                                                  float* __restrict__ out) {
    __shared__ _Float16 As[128][64];  // 16 KB
    __shared__ _Float16 Bs[128][64];  // 16 KB

    const int d0 = blockIdx.x * 128;
    const int k0 = blockIdx.y * 128;
    const int b = blockIdx.z;
    const int t = threadIdx.x;
    const int wave = t >> 6;
    const int lane = t & 63;
    const int wm = (wave >> 1) * 64;
    const int wn = (wave & 1) * 64;
    const int l15 = lane & 15;
    const int quad = lane >> 4;

    floatx4 acc[4][4] = {};

    const _Float16* Abase = St + ((size_t)b * KK + k0) * NN;
    const _Float16* Bbase = Xt + ((size_t)b * DD + d0) * NN;

    for (int n0 = 0; n0 < NN; n0 += 64) {
        __syncthreads();
        #pragma unroll
        for (int c = 0; c < 4; c++) {
            int u = c * 256 + t;                 // 16B unit index, 0..1023
            int r = u >> 3;
            int jc = ((u & 7) ^ (r & 7)) * 8;    // swizzled source column
            load_lds16(Abase + (size_t)r * NN + n0 + jc, (_Float16*)As + u * 8);
            load_lds16(Bbase + (size_t)r * NN + n0 + jc, (_Float16*)Bs + u * 8);
        }
        __syncthreads();
        #pragma unroll
        for (int s = 0; s < 2; s++) {
            half8 af[4], bf[4];
            #pragma unroll
            for (int i = 0; i < 4; i++) {
                int row = wm + i * 16 + l15;
                af[i] = *(half8*)&As[row][((s * 4 + quad) ^ (row & 7)) * 8];
            }
            #pragma unroll
            for (int i = 0; i < 4; i++) {
                int row = wn + i * 16 + l15;
                bf[i] = *(half8*)&Bs[row][((s * 4 + quad) ^ (row & 7)) * 8];
            }
            #pragma unroll
            for (int mi = 0; mi < 4; mi++)
                #pragma unroll
                for (int ni = 0; ni < 4; ni++)
                    acc[mi][ni] = __builtin_amdgcn_mfma_f32_16x16x32_f16(af[mi], bf[ni], acc[mi][ni], 0, 0, 0);
        }
    }

    #pragma unroll
    for (int ni = 0; ni < 4; ni++) {
        #pragma unroll
        for (int mi = 0; mi < 4; mi++) {
            int k = k0 + wm + mi * 16 + quad * 4;
            int d = d0 + wn + ni * 16 + l15;
            float* op = out + ((size_t)b * KK + k) * DD + d;
            floatx4 a = acc[mi][ni];
            op[0 * DD] = a[0];
            op[1 * DD] = a[1];
            op[2 * DD] = a[2];
            op[3 * DD] = a[3];
        }
    }
}

// ---------------------------------------------------------------------------
extern "C" void kernel_launch(void* const* d_in, const int* in_sizes, int n_in,
                              void* d_out, int out_size, void* d_ws, size_t ws_size,
                              hipStream_t stream) {
    const float* x  = (const float*)d_in[0];   // [B,N,D] fp32
    const float* cb = (const float*)d_in[1];   // [K,D] fp32
    float* out = (float*)d_out;                // [B,K,D] fp32

    char* ws = (char*)d_ws;
    float*    csq = (float*)ws;                                   // 4 KB
    _Float16* Cbh = (_Float16*)(ws + 4096);                       // 768 KB
    _Float16* Xt  = (_Float16*)(ws + 4096 + 786432);              // 48 MB [b][d][n]
    _Float16* St  = (_Float16*)(ws + 4096 + 786432 + 50331648);   // 32 MB [b][k][n]

    cast_f32_f16<<<(KK * DD / 8 + 255) / 256, 256, 0, stream>>>(cb, Cbh, KK * DD / 8);
    csq_kernel<<<KK, 256, 0, stream>>>(cb, csq);

    // fused logits + softmax -> St; also emits Xt (byproduct transpose)
    fused_logits_softmax<<<MM / 64, 512, 0, stream>>>(x, Cbh, csq, St, Xt);

    // aggregate
    gemm2_mfma<<<dim3(DD / 128, KK / 128, BB), 256, 0, stream>>>(St, Xt, out);
}